// Round 5
// baseline (101.380 us; speedup 1.0000x reference)
//
#include <hip/hip_runtime.h>

// STDP Linear layer: B=64, IN=4096, OUT=1024, all fp32.
// Outputs concatenated in d_out: spikes[64,1024] | mem[64,1024] |
// w_new[1024,4096] | tp[64,4096] | tq[64,1024]
//
// Kernel graph:  A(gemm1 splitK, partials into w_new region) -> B(post: reduce+LIF+tq+tp)
//                -> C(w_new rank-64 update)

#define B_    64
#define IN_   4096
#define OUT_  1024
#define SPLITS 64
#define BK    64    // k-chunk per block == KC (single chunk, one barrier)

static constexpr int OFF_SPIKES = 0;
static constexpr int OFF_MEM    = B_ * OUT_;               // 65536
static constexpr int OFF_W      = 2 * B_ * OUT_;           // 131072
static constexpr int OFF_TP     = OFF_W + OUT_ * IN_;      // 4325376
static constexpr int OFF_TQ    = OFF_TP + B_ * IN_;        // 4587520

// ---------------------------------------------------------------------------
// A: weighted partial GEMM.  grid (16 n-tiles, 64 k-splits), 128 threads.
// 64b x 64n tile, single BK=64 chunk, ONE barrier per block.
// acc 8x4 per thread (8 batches x 4 neurons): LDS reads 48 B per 32 FMA
// (1.5 B/FLOP) vs 2.0 for 4x4 — LDS-pipe relief.
// K-major staging with XOR swizzle col ^= 2*(k>>2) (identical math to the
// verified round-3 kernel; 8-wide A fragment = two quads at (b0)^sH and
// (b0+4)^sH, element pair-swap folded into the unrolled index).
// ---------------------------------------------------------------------------
__global__ __launch_bounds__(128) void k_gemm1(const float* __restrict__ A,
                                               const float* __restrict__ Wt,
                                               float* __restrict__ part) {
  const int nb = blockIdx.x;           // 0..15  (64-neuron tile)
  const int ks = blockIdx.y;           // 0..63  (64-k split)
  const int t  = threadIdx.x;          // 0..127

  __shared__ float At[BK][64];   // k-major: At[k][b ^ 2*(k>>2)]
  __shared__ float Wn[BK][64];   // k-major: Wn[k][n ^ 2*(k>>2)]

  const int col4 = t & 15;             // k-quad (staging)
  const int rowg = t >> 4;             // row group 0..7 (staging)
  const int k0   = ks * BK;

  // ---- load both 64x64 tiles into registers (coalesced float4) ----
  float4 av[8], wv[8];
#pragma unroll
  for (int p = 0; p < 8; ++p) {
    const int r = rowg + p * 8;
    av[p] = *reinterpret_cast<const float4*>(A  + (size_t)r * IN_ + k0 + col4 * 4);
    wv[p] = *reinterpret_cast<const float4*>(Wt + (size_t)(nb * 64 + r) * IN_ + k0 + col4 * 4);
  }

  // ---- transpose into k-major LDS with XOR swizzle ----
  const int sw = 2 * col4;
#pragma unroll
  for (int p = 0; p < 8; ++p) {
    const int r  = rowg + p * 8;
    const int cA = r ^ sw;
    At[col4 * 4 + 0][cA] = av[p].x;
    At[col4 * 4 + 1][cA] = av[p].y;
    At[col4 * 4 + 2][cA] = av[p].z;
    At[col4 * 4 + 3][cA] = av[p].w;
    Wn[col4 * 4 + 0][cA] = wv[p].x;
    Wn[col4 * 4 + 1][cA] = wv[p].y;
    Wn[col4 * 4 + 2][cA] = wv[p].z;
    Wn[col4 * 4 + 3][cA] = wv[p].w;
  }
  __syncthreads();                     // the only barrier

  const int bu8 = t >> 4;              // batch group 0..7 (8 batches each)
  const int nv4 = t & 15;              // neuron group 0..15 (4 neurons each)

  float acc[8][4];
#pragma unroll
  for (int u = 0; u < 8; ++u)
#pragma unroll
    for (int v = 0; v < 4; ++v) acc[u][v] = 0.f;

#pragma unroll
  for (int kq = 0; kq < BK / 4; ++kq) {
    const int sH = (2 * kq) & 28;      // address part of swizzle
    const int xe = (kq & 1) ? 2 : 0;   // element pair-swap (compile-time)
#pragma unroll
    for (int m = 0; m < 4; ++m) {
      const int kk = kq * 4 + m;
      const float4 a0 = *reinterpret_cast<const float4*>(&At[kk][(bu8 * 8 + 0) ^ sH]);
      const float4 a1 = *reinterpret_cast<const float4*>(&At[kk][(bu8 * 8 + 4) ^ sH]);
      const float4 w4 = *reinterpret_cast<const float4*>(&Wn[kk][(nv4 * 4) ^ sH]);
      const float a0e[4] = {a0.x, a0.y, a0.z, a0.w};
      const float a1e[4] = {a1.x, a1.y, a1.z, a1.w};
      const float we [4] = {w4.x, w4.y, w4.z, w4.w};
#pragma unroll
      for (int u = 0; u < 8; ++u) {
        const float au = (u < 4) ? a0e[(u ^ xe) & 3] : a1e[((u - 4) ^ xe) & 3];
#pragma unroll
        for (int v = 0; v < 4; ++v)
          acc[u][v] = fmaf(au, we[(v ^ xe) & 3], acc[u][v]);
      }
    }
  }

  // ---- write partials: part[ks][b][n], float4, coalesced ----
#pragma unroll
  for (int u = 0; u < 8; ++u) {
    const int b = bu8 * 8 + u;
    float4 r;
    r.x = acc[u][0]; r.y = acc[u][1]; r.z = acc[u][2]; r.w = acc[u][3];
    *reinterpret_cast<float4*>(
        part + ((size_t)(ks * 64 + b)) * OUT_ + nb * 64 + nv4 * 4) = r;
  }
}

// ---------------------------------------------------------------------------
// B: fused post-pass.  65536 threads: per-thread LIF (reduce 64 partials,
// deterministic order) + tq, AND one float4 of tp.
// ---------------------------------------------------------------------------
__global__ __launch_bounds__(256) void k_post(const float* __restrict__ part,
                                              const float* __restrict__ membrane,
                                              const float* __restrict__ trace_post,
                                              const float* __restrict__ in_spikes,
                                              const float* __restrict__ trace_pre,
                                              float* __restrict__ out) {
  const int t = blockIdx.x * 256 + threadIdx.x;   // 0..65535
  const int b = t >> 10;
  const int n = t & (OUT_ - 1);

  float s0 = 0.f, s1 = 0.f, s2 = 0.f, s3 = 0.f;
#pragma unroll
  for (int ks = 0; ks < SPLITS; ks += 4) {
    s0 += part[((size_t)((ks + 0) * B_ + b)) * OUT_ + n];
    s1 += part[((size_t)((ks + 1) * B_ + b)) * OUT_ + n];
    s2 += part[((size_t)((ks + 2) * B_ + b)) * OUT_ + n];
    s3 += part[((size_t)((ks + 3) * B_ + b)) * OUT_ + n];
  }
  const float weighted = (s0 + s1) + (s2 + s3);

  const float mem   = fmaf(membrane[t], 0.98f, weighted);
  const float spike = (mem > 0.4f) ? 1.0f : 0.0f;
  const float memo  = (spike > 0.0f) ? 0.0f : mem;
  float tq = fmaf(trace_post[n], 0.85f, spike);
  tq = fminf(fmaxf(tq, 0.0f), 1.0f);

  out[OFF_SPIKES + t] = spike;
  out[OFF_MEM    + t] = memo;
  out[OFF_TQ     + t] = tq;

  // tp: one float4 per thread (64*4096/4 = 65536 float4)
  const int i4 = t & (IN_ / 4 - 1);
  const float4 x  = reinterpret_cast<const float4*>(in_spikes)[t];
  const float4 tr = reinterpret_cast<const float4*>(trace_pre)[i4];
  float4 r;
  r.x = fminf(fmaxf(fmaf(tr.x, 0.85f, x.x), 0.0f), 1.0f);
  r.y = fminf(fmaxf(fmaf(tr.y, 0.85f, x.y), 0.0f), 1.0f);
  r.z = fminf(fmaxf(fmaf(tr.z, 0.85f, x.z), 0.0f), 1.0f);
  r.w = fminf(fmaxf(fmaf(tr.w, 0.85f, x.w), 0.0f), 1.0f);
  reinterpret_cast<float4*>(out + OFF_TP)[t] = r;
}

// ---------------------------------------------------------------------------
// C: w_new = clip(weight + 0.001 * tq^T tp, -0.1, 0.5).   (unchanged)
// grid (64 i-tiles, 16 o-tiles), 256 threads, 64x64 tile, 16 acc/thread.
// ---------------------------------------------------------------------------
__global__ __launch_bounds__(256) void k_wnew(const float* __restrict__ weight,
                                              const float* __restrict__ tp,
                                              const float* __restrict__ tq,
                                              float* __restrict__ wout) {
  const int i0 = blockIdx.x * 64;
  const int o0 = blockIdx.y * 64;

  __shared__ float tpl[64][68];
  __shared__ float tql[64][68];
  {
    const int c4 = threadIdx.x & 15;
    const int rr = threadIdx.x >> 4;
#pragma unroll
    for (int r = 0; r < 4; ++r) {
      const int b = rr + r * 16;
      *reinterpret_cast<float4*>(&tpl[b][c4 * 4]) =
          *reinterpret_cast<const float4*>(tp + (size_t)b * IN_  + i0 + c4 * 4);
      *reinterpret_cast<float4*>(&tql[b][c4 * 4]) =
          *reinterpret_cast<const float4*>(tq + (size_t)b * OUT_ + o0 + c4 * 4);
    }
  }
  __syncthreads();

  const int il = threadIdx.x & 15;   // i-group: i = i0 + il*4 + v
  const int ol = threadIdx.x >> 4;   // o-group: o = o0 + ol*4 + u

  float acc[4][4];
#pragma unroll
  for (int u = 0; u < 4; ++u)
#pragma unroll
    for (int v = 0; v < 4; ++v) acc[u][v] = 0.f;

#pragma unroll 4
  for (int b = 0; b < 64; ++b) {
    const float4 tpv = *reinterpret_cast<const float4*>(&tpl[b][il * 4]);
    const float4 tqv = *reinterpret_cast<const float4*>(&tql[b][ol * 4]);
    const float tp4[4] = {tpv.x, tpv.y, tpv.z, tpv.w};
    const float tq4[4] = {tqv.x, tqv.y, tqv.z, tqv.w};
#pragma unroll
    for (int u = 0; u < 4; ++u)
#pragma unroll
      for (int v = 0; v < 4; ++v)
        acc[u][v] = fmaf(tq4[u], tp4[v], acc[u][v]);
  }

  const float cdw = (float)(0.005 - 0.004);   // A_POS - A_NEG
#pragma unroll
  for (int u = 0; u < 4; ++u) {
    const int o = o0 + ol * 4 + u;
    const float4 wv = *reinterpret_cast<const float4*>(
        weight + (size_t)o * IN_ + i0 + il * 4);
    float4 r;
    r.x = fminf(fmaxf(fmaf(cdw, acc[u][0], wv.x), -0.1f), 0.5f);
    r.y = fminf(fmaxf(fmaf(cdw, acc[u][1], wv.y), -0.1f), 0.5f);
    r.z = fminf(fmaxf(fmaf(cdw, acc[u][2], wv.z), -0.1f), 0.5f);
    r.w = fminf(fmaxf(fmaf(cdw, acc[u][3], wv.w), -0.1f), 0.5f);
    *reinterpret_cast<float4*>(wout + (size_t)o * IN_ + i0 + il * 4) = r;
  }
}

// ---------------------------------------------------------------------------
extern "C" void kernel_launch(void* const* d_in, const int* in_sizes, int n_in,
                              void* d_out, int out_size, void* d_ws, size_t ws_size,
                              hipStream_t stream) {
  const float* in_spikes  = (const float*)d_in[0];
  const float* weight     = (const float*)d_in[1];
  const float* membrane   = (const float*)d_in[2];
  const float* trace_pre  = (const float*)d_in[3];
  const float* trace_post = (const float*)d_in[4];
  float* out = (float*)d_out;

  // Split-K partials (64 splits x 64 b x 1024 n x 4B = 16.78 MB) exactly fill
  // the w_new output region (1024*4096*4 = 16.78 MB); consumed by k_post
  // before k_wnew overwrites the region with the real w_new.
  float* part = out + OFF_W;

  k_gemm1<<<dim3(16, SPLITS), 128, 0, stream>>>(in_spikes, weight, part);
  k_post <<<dim3(256),        256, 0, stream>>>(part, membrane, trace_post,
                                                in_spikes, trace_pre, out);
  k_wnew <<<dim3(64, 16),     256, 0, stream>>>(weight, out + OFF_TP,
                                                out + OFF_TQ, out + OFF_W);
}

// Round 7
// 93.644 us; speedup vs baseline: 1.0826x; 1.0826x over previous
//
#include <hip/hip_runtime.h>

// STDP Linear layer: B=64, IN=4096, OUT=1024, all fp32.
// Outputs concatenated in d_out: spikes[64,1024] | mem[64,1024] |
// w_new[1024,4096] | tp[64,4096] | tq[64,1024]
//
// gemm1 runs on MFMA via bf16 hi/lo split (3 passes: hh + hl + lh).
// Error budget: ~1e-5 abs vs the 3.9e-3 absmax we already pass with.

#define B_    64
#define IN_   4096
#define OUT_  1024
#define SPLITS 32
#define KC    128   // k-range per block
#define BK    64    // k-chunk staged in LDS

static constexpr int OFF_SPIKES = 0;
static constexpr int OFF_MEM    = B_ * OUT_;               // 65536
static constexpr int OFF_W      = 2 * B_ * OUT_;           // 131072
static constexpr int OFF_TP     = OFF_W + OUT_ * IN_;      // 4325376
static constexpr int OFF_TQ     = OFF_TP + B_ * IN_;       // 4587520

typedef short          s16x8 __attribute__((ext_vector_type(8)));
typedef unsigned short u16x8 __attribute__((ext_vector_type(8)));
typedef float          f32x4 __attribute__((ext_vector_type(4)));

__device__ __forceinline__ unsigned short bf16_rne(float x) {
  unsigned u = __float_as_uint(x);
  return (unsigned short)((u + 0x7fffu + ((u >> 16) & 1u)) >> 16);
}

// ---------------------------------------------------------------------------
// A: weighted partial GEMM on MFMA.  grid (16 n-tiles, 32 k-splits), 256 thr.
// Per block: 64b x 64n x 128k, two BK=64 chunks.
// LDS: Ah/Al/Wh/Wl [64 rows][64 k] bf16 (8 KB each, 32 KB total), 16B-chunk
// XOR swizzle: chunk j of row r stored at j ^ (r&7)  (reads: 2-way = free).
// Wave w: n-strip w*16, 4 b-tiles; acc[bt] = sum over k of
//   Ahi*Whi + Ahi*Wlo + Alo*Whi  (mfma_f32_16x16x32_bf16).
// A-frag: lane holds row=lane&15, k=(lane>>4)*8..+7.
// C/D map (m89-verified): col = lane&15 (n), row = (lane>>4)*4+reg (b).
// ---------------------------------------------------------------------------
__global__ __launch_bounds__(256) void k_gemm1(const float* __restrict__ A,
                                               const float* __restrict__ Wt,
                                               float* __restrict__ part) {
  const int nb   = blockIdx.x;   // 0..15
  const int ks   = blockIdx.y;   // 0..31
  const int t    = threadIdx.x;
  const int lane = t & 63;
  const int w    = t >> 6;

  __shared__ unsigned short Ah[64][64], Al[64][64], Wh[64][64], Wl[64][64];

  f32x4 acc[4];
#pragma unroll
  for (int bt = 0; bt < 4; ++bt) acc[bt] = (f32x4){0.f, 0.f, 0.f, 0.f};

#pragma unroll
  for (int c = 0; c < 2; ++c) {
    const int k0 = ks * KC + c * BK;

    // ---- stage: fp32 -> bf16 hi/lo, swizzled 16B chunks ----
    // 512 chunk-tasks per matrix (64 rows x 8 chunks of 8 k), 2 per thread.
#pragma unroll
    for (int s = t; s < 512; s += 256) {
      const int r  = s >> 3;
      const int j  = s & 7;
      const int jc = (j ^ (r & 7)) << 3;     // dest column (u16 units)

      const float* ap = A + (size_t)r * IN_ + k0 + j * 8;
      const float4 a0 = *reinterpret_cast<const float4*>(ap);
      const float4 a1 = *reinterpret_cast<const float4*>(ap + 4);
      const float  af[8] = {a0.x, a0.y, a0.z, a0.w, a1.x, a1.y, a1.z, a1.w};
      u16x8 ahi, alo;
#pragma unroll
      for (int e = 0; e < 8; ++e) {
        const unsigned short h = bf16_rne(af[e]);
        ahi[e] = h;
        alo[e] = bf16_rne(af[e] - __uint_as_float(((unsigned)h) << 16));
      }
      *reinterpret_cast<u16x8*>(&Ah[r][jc]) = ahi;
      *reinterpret_cast<u16x8*>(&Al[r][jc]) = alo;

      const float* wp = Wt + (size_t)(nb * 64 + r) * IN_ + k0 + j * 8;
      const float4 w0 = *reinterpret_cast<const float4*>(wp);
      const float4 w1 = *reinterpret_cast<const float4*>(wp + 4);
      const float  wf[8] = {w0.x, w0.y, w0.z, w0.w, w1.x, w1.y, w1.z, w1.w};
      u16x8 whi, wlo;
#pragma unroll
      for (int e = 0; e < 8; ++e) {
        const unsigned short h = bf16_rne(wf[e]);
        whi[e] = h;
        wlo[e] = bf16_rne(wf[e] - __uint_as_float(((unsigned)h) << 16));
      }
      *reinterpret_cast<u16x8*>(&Wh[r][jc]) = whi;
      *reinterpret_cast<u16x8*>(&Wl[r][jc]) = wlo;
    }
    __syncthreads();

    // ---- MFMA: two k-steps of 32 per chunk ----
#pragma unroll
    for (int kk = 0; kk < 2; ++kk) {
      const int c4 = kk * 4 + (lane >> 4);       // 16B-chunk index 0..7
      const int jc = (c4 ^ (lane & 7)) << 3;     // swizzled column
      const int nloc = w * 16 + (lane & 15);

      const s16x8 whi = *reinterpret_cast<const s16x8*>(&Wh[nloc][jc]);
      const s16x8 wlo = *reinterpret_cast<const s16x8*>(&Wl[nloc][jc]);
#pragma unroll
      for (int bt = 0; bt < 4; ++bt) {
        const int bloc = bt * 16 + (lane & 15);
        const s16x8 ahi = *reinterpret_cast<const s16x8*>(&Ah[bloc][jc]);
        const s16x8 alo = *reinterpret_cast<const s16x8*>(&Al[bloc][jc]);
        acc[bt] = __builtin_amdgcn_mfma_f32_16x16x32_bf16(ahi, whi, acc[bt], 0, 0, 0);
        acc[bt] = __builtin_amdgcn_mfma_f32_16x16x32_bf16(ahi, wlo, acc[bt], 0, 0, 0);
        acc[bt] = __builtin_amdgcn_mfma_f32_16x16x32_bf16(alo, whi, acc[bt], 0, 0, 0);
      }
    }
    if (c == 0) __syncthreads();   // LDS reuse by next chunk
  }

  // ---- write partials: part[ks][b][n] ----
  const int n_g = nb * 64 + w * 16 + (lane & 15);
#pragma unroll
  for (int bt = 0; bt < 4; ++bt) {
#pragma unroll
    for (int reg = 0; reg < 4; ++reg) {
      const int b = bt * 16 + (lane >> 4) * 4 + reg;
      part[((size_t)(ks * 64 + b)) * OUT_ + n_g] = acc[bt][reg];
    }
  }
}

// ---------------------------------------------------------------------------
// B: fused post-pass.  65536 threads: per-thread LIF (reduce 32 partials,
// deterministic order) + tq, AND one float4 of tp.
// ---------------------------------------------------------------------------
__global__ __launch_bounds__(256) void k_post(const float* __restrict__ part,
                                              const float* __restrict__ membrane,
                                              const float* __restrict__ trace_post,
                                              const float* __restrict__ in_spikes,
                                              const float* __restrict__ trace_pre,
                                              float* __restrict__ out) {
  const int t = blockIdx.x * 256 + threadIdx.x;   // 0..65535
  const int b = t >> 10;
  const int n = t & (OUT_ - 1);

  float s0 = 0.f, s1 = 0.f, s2 = 0.f, s3 = 0.f;
#pragma unroll
  for (int ks = 0; ks < SPLITS; ks += 4) {
    s0 += part[((size_t)((ks + 0) * B_ + b)) * OUT_ + n];
    s1 += part[((size_t)((ks + 1) * B_ + b)) * OUT_ + n];
    s2 += part[((size_t)((ks + 2) * B_ + b)) * OUT_ + n];
    s3 += part[((size_t)((ks + 3) * B_ + b)) * OUT_ + n];
  }
  const float weighted = (s0 + s1) + (s2 + s3);

  const float mem   = fmaf(membrane[t], 0.98f, weighted);
  const float spike = (mem > 0.4f) ? 1.0f : 0.0f;
  const float memo  = (spike > 0.0f) ? 0.0f : mem;
  float tq = fmaf(trace_post[n], 0.85f, spike);
  tq = fminf(fmaxf(tq, 0.0f), 1.0f);

  out[OFF_SPIKES + t] = spike;
  out[OFF_MEM    + t] = memo;
  out[OFF_TQ     + t] = tq;

  // tp: one float4 per thread (64*4096/4 = 65536 float4)
  const int i4 = t & (IN_ / 4 - 1);
  const float4 x  = reinterpret_cast<const float4*>(in_spikes)[t];
  const float4 tr = reinterpret_cast<const float4*>(trace_pre)[i4];
  float4 r;
  r.x = fminf(fmaxf(fmaf(tr.x, 0.85f, x.x), 0.0f), 1.0f);
  r.y = fminf(fmaxf(fmaf(tr.y, 0.85f, x.y), 0.0f), 1.0f);
  r.z = fminf(fmaxf(fmaf(tr.z, 0.85f, x.z), 0.0f), 1.0f);
  r.w = fminf(fmaxf(fmaf(tr.w, 0.85f, x.w), 0.0f), 1.0f);
  reinterpret_cast<float4*>(out + OFF_TP)[t] = r;
}

// ---------------------------------------------------------------------------
// C: w_new = clip(weight + 0.001 * tq^T tp, -0.1, 0.5).   (unchanged, verified)
// grid (64 i-tiles, 16 o-tiles), 256 threads, 64x64 tile, 16 acc/thread.
// ---------------------------------------------------------------------------
__global__ __launch_bounds__(256) void k_wnew(const float* __restrict__ weight,
                                              const float* __restrict__ tp,
                                              const float* __restrict__ tq,
                                              float* __restrict__ wout) {
  const int i0 = blockIdx.x * 64;
  const int o0 = blockIdx.y * 64;

  __shared__ float tpl[64][68];
  __shared__ float tql[64][68];
  {
    const int c4 = threadIdx.x & 15;
    const int rr = threadIdx.x >> 4;
#pragma unroll
    for (int r = 0; r < 4; ++r) {
      const int b = rr + r * 16;
      *reinterpret_cast<float4*>(&tpl[b][c4 * 4]) =
          *reinterpret_cast<const float4*>(tp + (size_t)b * IN_  + i0 + c4 * 4);
      *reinterpret_cast<float4*>(&tql[b][c4 * 4]) =
          *reinterpret_cast<const float4*>(tq + (size_t)b * OUT_ + o0 + c4 * 4);
    }
  }
  __syncthreads();

  const int il = threadIdx.x & 15;   // i-group: i = i0 + il*4 + v
  const int ol = threadIdx.x >> 4;   // o-group: o = o0 + ol*4 + u

  float acc[4][4];
#pragma unroll
  for (int u = 0; u < 4; ++u)
#pragma unroll
    for (int v = 0; v < 4; ++v) acc[u][v] = 0.f;

#pragma unroll 4
  for (int b = 0; b < 64; ++b) {
    const float4 tpv = *reinterpret_cast<const float4*>(&tpl[b][il * 4]);
    const float4 tqv = *reinterpret_cast<const float4*>(&tql[b][ol * 4]);
    const float tp4[4] = {tpv.x, tpv.y, tpv.z, tpv.w};
    const float tq4[4] = {tqv.x, tqv.y, tqv.z, tqv.w};
#pragma unroll
    for (int u = 0; u < 4; ++u)
#pragma unroll
      for (int v = 0; v < 4; ++v)
        acc[u][v] = fmaf(tq4[u], tp4[v], acc[u][v]);
  }

  const float cdw = (float)(0.005 - 0.004);   // A_POS - A_NEG
#pragma unroll
  for (int u = 0; u < 4; ++u) {
    const int o = o0 + ol * 4 + u;
    const float4 wv = *reinterpret_cast<const float4*>(
        weight + (size_t)o * IN_ + i0 + il * 4);
    float4 r;
    r.x = fminf(fmaxf(fmaf(cdw, acc[u][0], wv.x), -0.1f), 0.5f);
    r.y = fminf(fmaxf(fmaf(cdw, acc[u][1], wv.y), -0.1f), 0.5f);
    r.z = fminf(fmaxf(fmaf(cdw, acc[u][2], wv.z), -0.1f), 0.5f);
    r.w = fminf(fmaxf(fmaf(cdw, acc[u][3], wv.w), -0.1f), 0.5f);
    *reinterpret_cast<float4*>(wout + (size_t)o * IN_ + i0 + il * 4) = r;
  }
}

// ---------------------------------------------------------------------------
extern "C" void kernel_launch(void* const* d_in, const int* in_sizes, int n_in,
                              void* d_out, int out_size, void* d_ws, size_t ws_size,
                              hipStream_t stream) {
  const float* in_spikes  = (const float*)d_in[0];
  const float* weight     = (const float*)d_in[1];
  const float* membrane   = (const float*)d_in[2];
  const float* trace_pre  = (const float*)d_in[3];
  const float* trace_post = (const float*)d_in[4];
  float* out = (float*)d_out;

  // Split-K partials (32 x 64 x 1024 x 4B = 8.4 MB) live in the w_new output
  // region (16.8 MB); consumed by k_post before k_wnew overwrites the region.
  float* part = out + OFF_W;

  k_gemm1<<<dim3(16, SPLITS), 256, 0, stream>>>(in_spikes, weight, part);
  k_post <<<dim3(256),        256, 0, stream>>>(part, membrane, trace_post,
                                                in_spikes, trace_pre, out);
  k_wnew <<<dim3(64, 16),     256, 0, stream>>>(weight, out + OFF_TP,
                                                out + OFF_TQ, out + OFF_W);
}